// Round 1
// baseline (35.413 us; speedup 1.0000x reference)
//
#include <hip/hip_runtime.h>

// gen_En: En[g] = sum over waveguides i covering g of sum_m eta[i,m]*U[i,m]*Ey[i,m,f]
//   eta = neff/(neff+1), f = g - 64 - 128*i, window 1024, stride 128 (overlap 8).
// Gather formulation: each Ey element is consumed exactly once, no atomics.

#define MODES 6
#define RES 128
#define NWG 8192
#define EY_SIZE 1024
#define TOTAL_SIZE ((NWG + 8) * RES)   // 1,049,600

// 256 threads/block, 4 outputs/thread -> 1024 outputs/block, 1025 blocks exact.
__global__ __launch_bounds__(256) void gen_en_gather(
    const float* __restrict__ U,
    const float* __restrict__ neff,
    const float* __restrict__ Ey,
    float* __restrict__ En)
{
    // Per-block weights: at most 16 waveguides touch this block's 1024 outputs.
    __shared__ float w[96];

    const int g_blk = blockIdx.x << 10;          // 1024 outputs per block
    const int tb = g_blk - 64;
    int i_lo_blk = (tb >= 0 ? (tb >> 7) : -1) - 7;
    if (i_lo_blk < 0) i_lo_blk = 0;
    int i_hi_blk = (g_blk + 1023 - 64) >> 7;     // always >= 0
    if (i_hi_blk > NWG - 1) i_hi_blk = NWG - 1;

    const int t = threadIdx.x;
    if (t < 96) {
        const int di = t / 6;
        const int m  = t - di * 6;
        const int i  = i_lo_blk + di;
        float v = 0.0f;
        if (i <= i_hi_blk) {
            const float nf = neff[i * MODES + m];
            v = nf / (nf + 1.0f) * U[i * MODES + m];   // eta * U
        }
        w[t] = v;
    }
    __syncthreads();

    const int g0 = g_blk + (t << 2);             // multiple of 4
    const int tg = g0 - 64;                      // multiple of 4
    int ihi = (tg >= 0) ? (tg >> 7) : -1;
    int ilo = ihi - 7;
    if (ilo < 0) ilo = 0;
    if (ihi > NWG - 1) ihi = NWG - 1;

    float4 acc = make_float4(0.0f, 0.0f, 0.0f, 0.0f);

    for (int i = ilo; i <= ihi; ++i) {
        const int f0 = tg - (i << 7);            // in [0,1020], multiple of 4
        const float* ey = Ey + (size_t)i * (MODES * EY_SIZE) + f0;
        const int wbase = (i - i_lo_blk) * MODES;
        #pragma unroll
        for (int m = 0; m < MODES; ++m) {
            const float4 e = *reinterpret_cast<const float4*>(ey + m * EY_SIZE);
            const float wm = w[wbase + m];
            acc.x += wm * e.x;
            acc.y += wm * e.y;
            acc.z += wm * e.z;
            acc.w += wm * e.w;
        }
    }

    *reinterpret_cast<float4*>(En + g0) = acc;   // covers every output element:
                                                 // zero where no window overlaps
}

extern "C" void kernel_launch(void* const* d_in, const int* in_sizes, int n_in,
                              void* d_out, int out_size, void* d_ws, size_t ws_size,
                              hipStream_t stream) {
    // inputs (setup_inputs order): hs (unused), U, neff, Ey — all float32
    const float* U    = (const float*)d_in[1];
    const float* neff = (const float*)d_in[2];
    const float* Ey   = (const float*)d_in[3];
    float* En = (float*)d_out;

    const int blocks = TOTAL_SIZE / 1024;        // 1025, exact tiling
    gen_en_gather<<<blocks, 256, 0, stream>>>(U, neff, Ey, En);
}